// Round 11
// baseline (399.259 us; speedup 1.0000x reference)
//
#include <hip/hip_runtime.h>
#include <hip/hip_bf16.h>

#define N_NODES 50000
#define N_EDGES 800000
#define F 64
#define N_GRAPHS 500
#define NW ((N_NODES + 63) / 64)   // 782 node-tiles of 64
#define PADW 68                    // A-tile pad (float4-aligned): bank-grp (lane+kc/4)%8 -> even
#define FILL_PASSES 4
#define FILL_RANGE ((N_NODES + FILL_PASSES - 1) / FILL_PASSES)   // 12500 dst per pass

// ---------------- CSR build step 1: deg[dst]++ ----------------
__global__ __launch_bounds__(256) void hist_kernel(
    const int* __restrict__ edge, int* __restrict__ deg)
{
    int e = blockIdx.x * 256 + threadIdx.x;
    if (e < N_EDGES) atomicAdd(&deg[edge[N_EDGES + e]], 1);
}

// ---------------- CSR build step 2a: per-64-chunk sums ----------------
__global__ __launch_bounds__(256) void wavesum_kernel(
    const int* __restrict__ deg, int* __restrict__ partial)
{
    int w = (blockIdx.x * 256 + threadIdx.x) >> 6;
    int lane = threadIdx.x & 63;
    if (w >= NW) return;
    int i = w * 64 + lane;
    int v = (i < N_NODES) ? deg[i] : 0;
#pragma unroll
    for (int d = 32; d > 0; d >>= 1) v += __shfl_xor(v, d);
    if (lane == 0) partial[w] = v;
}

// ---------------- CSR build step 2b: single-block exclusive scan of partial[NW] ----------------
__global__ __launch_bounds__(1024) void scanp_kernel(int* __restrict__ partial)
{
    __shared__ int ws[16];
    int t = threadIdx.x, lane = t & 63, wv = t >> 6;
    int v = (t < NW) ? partial[t] : 0;
    int incl = v;
#pragma unroll
    for (int d = 1; d < 64; d <<= 1) { int u = __shfl_up(incl, d); if (lane >= d) incl += u; }
    if (lane == 63) ws[wv] = incl;
    __syncthreads();
    if (wv == 0 && lane < 16) {
        int s = ws[lane];
#pragma unroll
        for (int d = 1; d < 16; d <<= 1) { int u = __shfl_up(s, d); if (lane >= d) s += u; }
        ws[lane] = s;
    }
    __syncthreads();
    int base = wv ? ws[wv - 1] : 0;
    if (t < NW) partial[t] = base + incl - v;     // exclusive scan in place
    if (t == 0) partial[NW] = ws[15];             // grand total
}

// ---------------- CSR build step 2c: per-chunk offsets ----------------
__global__ __launch_bounds__(256) void offsets_kernel(
    const int* __restrict__ deg, const int* __restrict__ partial,
    int* __restrict__ off, int* __restrict__ cursor)
{
    int w = (blockIdx.x * 256 + threadIdx.x) >> 6;
    int lane = threadIdx.x & 63;
    if (w >= NW) return;
    int i = w * 64 + lane;
    int v = (i < N_NODES) ? deg[i] : 0;
    int incl = v;
#pragma unroll
    for (int d = 1; d < 64; d <<= 1) { int u = __shfl_up(incl, d); if (lane >= d) incl += u; }
    int excl = partial[w] + incl - v;
    if (i < N_NODES) { off[i] = excl; cursor[i] = excl; }
    if (w == 0 && lane == 0) off[N_NODES] = partial[NW];
}

// ---------------- CSR build step 3: fill src lists, dst-range pass ----------------
// Pass p handles dst in [lo, lo+FILL_RANGE): csr write region is ~800KB -> L2-resident,
// lines fill completely before eviction (round-10 showed 51.6MB HBM writes for 3.2MB payload).
__global__ __launch_bounds__(256) void fill_kernel(
    const int* __restrict__ edge, int* __restrict__ cursor, int* __restrict__ csr_src, int lo)
{
    int e = blockIdx.x * 256 + threadIdx.x;
    if (e < N_EDGES) {
        int dst = edge[N_EDGES + e];
        if (dst >= lo && dst < lo + FILL_RANGE) {
            int slot = atomicAdd(&cursor[dst], 1);
            csr_src[slot] = edge[e];
        }
    }
}

// ---------------- gather v3: half-wave per node, 8 row-loads in flight per lane ----------------
// 32 lanes per node: 2 slot-groups x 16 feature-lanes (float4). Slots g+2k, k=0..7 -> 16
// slots per iteration, 8 independent accumulators = 8 outstanding loads/lane (2x round-10 MLP).
__global__ __launch_bounds__(256) void gather_kernel(
    const float* __restrict__ xin, const int* __restrict__ off,
    const int* __restrict__ csr_src, float* __restrict__ agg)
{
    int hw = (blockIdx.x * 256 + threadIdx.x) >> 5;   // half-wave id = node
    if (hw >= N_NODES) return;
    int hl = threadIdx.x & 31;
    int g = hl >> 4;              // slot parity 0/1
    int q = (hl & 15) << 2;       // feature quad offset

    int beg = off[hw], end = off[hw + 1];
    float4 A0 = make_float4(0.f, 0.f, 0.f, 0.f);
    float4 A1 = A0, A2 = A0, A3 = A0, A4 = A0, A5 = A0, A6 = A0, A7 = A0;

    for (int base = beg; base < end; base += 16) {
#define GSTEP(K, ACC) { int e = base + g + 2 * (K); if (e < end) { \
        const float4 v = *reinterpret_cast<const float4*>(xin + (size_t)csr_src[e] * F + q); \
        ACC.x += v.x; ACC.y += v.y; ACC.z += v.z; ACC.w += v.w; } }
        GSTEP(0, A0) GSTEP(1, A1) GSTEP(2, A2) GSTEP(3, A3)
        GSTEP(4, A4) GSTEP(5, A5) GSTEP(6, A6) GSTEP(7, A7)
#undef GSTEP
    }
    float4 s;
    s.x = ((A0.x + A1.x) + (A2.x + A3.x)) + ((A4.x + A5.x) + (A6.x + A7.x));
    s.y = ((A0.y + A1.y) + (A2.y + A3.y)) + ((A4.y + A5.y) + (A6.y + A7.y));
    s.z = ((A0.z + A1.z) + (A2.z + A3.z)) + ((A4.z + A5.z) + (A6.z + A7.z));
    s.w = ((A0.w + A1.w) + (A2.w + A3.w)) + ((A4.w + A5.w) + (A6.w + A7.w));
    // combine the two slot-groups (lanes differing in bit 4)
    s.x += __shfl_xor(s.x, 16);
    s.y += __shfl_xor(s.y, 16);
    s.z += __shfl_xor(s.z, 16);
    s.w += __shfl_xor(s.w, 16);
    if (hl < 16)
        *reinterpret_cast<float4*>(agg + (size_t)hw * F + q) = s;
}

// ---------------- gemm v2: both operands from LDS (unchanged from round 10) ----------------
__global__ __launch_bounds__(256) void gemm_kernel(
    const float* __restrict__ agg, const float* __restrict__ xin,
    const float* __restrict__ Wrel, const float* __restrict__ brel,
    const float* __restrict__ Wroot, float* __restrict__ out, int do_relu)
{
    __shared__ float sA[64 * PADW];
    __shared__ float sX[64 * PADW];
    __shared__ float sWrel[64 * 64];
    __shared__ float sWroot[64 * 64];

    int tid = threadIdx.x;
    int n0 = blockIdx.x * 64;

    // ---- stage A and X tiles (coalesced float4) ----
    for (int i = tid; i < 64 * 16; i += 256) {
        int row = i >> 4, c4 = (i & 15) << 2;
        int node = n0 + row;
        float4 va = make_float4(0.f, 0.f, 0.f, 0.f), vx = va;
        if (node < N_NODES) {
            va = *reinterpret_cast<const float4*>(agg + (size_t)node * F + c4);
            vx = *reinterpret_cast<const float4*>(xin + (size_t)node * F + c4);
        }
        *reinterpret_cast<float4*>(sA + row * PADW + c4) = va;
        *reinterpret_cast<float4*>(sX + row * PADW + c4) = vx;
    }
    // ---- stage W matrices (flat 16 KB each) ----
    for (int i = tid; i < 64 * 16; i += 256) {
        int idx = i << 2;
        *reinterpret_cast<float4*>(sWrel + idx)  = *reinterpret_cast<const float4*>(Wrel + idx);
        *reinterpret_cast<float4*>(sWroot + idx) = *reinterpret_cast<const float4*>(Wroot + idx);
    }
    __syncthreads();

    // ---- compute: lane = node-in-tile, wave owns 16 outputs ----
    int lane = tid & 63;
    int ob = __builtin_amdgcn_readfirstlane((tid >> 6) * 16);
    int n = n0 + lane;

    float acc[16];
#pragma unroll
    for (int j = 0; j < 16; ++j) acc[j] = brel[ob + j];   // uniform -> s_load

#pragma unroll
    for (int half = 0; half < 2; ++half) {
        const float* __restrict__ sW = half ? sWroot : sWrel;
        const float* __restrict__ s  = half ? sX : sA;
#pragma unroll
        for (int kc = 0; kc < F; kc += 4) {
            float4 a = *reinterpret_cast<const float4*>(s + lane * PADW + kc);
#pragma unroll
            for (int j = 0; j < 16; ++j) {
                // uniform LDS address -> broadcast ds_read_b128 (no bank conflict)
                float4 wv = *reinterpret_cast<const float4*>(sW + (ob + j) * F + kc);
                acc[j] += a.x * wv.x + a.y * wv.y + a.z * wv.z + a.w * wv.w;
            }
        }
    }
    if (do_relu) {
#pragma unroll
        for (int j = 0; j < 16; ++j) acc[j] = fmaxf(acc[j], 0.f);
    }
    if (n < N_NODES) {
#pragma unroll
        for (int j = 0; j < 16; j += 4)
            *reinterpret_cast<float4*>(out + (size_t)n * F + ob + j) =
                make_float4(acc[j], acc[j + 1], acc[j + 2], acc[j + 3]);
    }
}

// ---------------- fused pool (mean over contiguous node range) + head ----------------
__global__ __launch_bounds__(256) void pool_head_kernel(
    const float* __restrict__ h,
    const int* __restrict__ batch,   // sorted
    const float* __restrict__ Wlin,  // [2][64]
    const float* __restrict__ blin,  // [2]
    float* __restrict__ out)         // [N_GRAPHS][2]
{
    __shared__ float psum[4][F];
    __shared__ float pooled[F];
    int g = blockIdx.x;
    int tid = threadIdx.x, wave = tid >> 6, lane = tid & 63;

    int lo = 0, hi = N_NODES;
    while (lo < hi) { int mid = (lo + hi) >> 1; if (batch[mid] < g) lo = mid + 1; else hi = mid; }
    int s = lo;
    hi = N_NODES;
    while (lo < hi) { int mid = (lo + hi) >> 1; if (batch[mid] < g + 1) lo = mid + 1; else hi = mid; }
    int e = lo;

    float acc = 0.f;
    for (int n = s + wave; n < e; n += 4) acc += h[n * F + lane];
    psum[wave][lane] = acc;
    __syncthreads();
    if (wave == 0) {
        float p = psum[0][lane] + psum[1][lane] + psum[2][lane] + psum[3][lane];
        float c = (float)(e - s);
        pooled[lane] = p / fmaxf(c, 1.0f);
    }
    __syncthreads();
    if (tid < 2) {
        float acc2 = 0.f;
#pragma unroll
        for (int k = 0; k < F; ++k) acc2 += pooled[k] * Wlin[tid * F + k];
        out[g * 2 + tid] = acc2 + blin[tid];
    }
}

extern "C" void kernel_launch(void* const* d_in, const int* in_sizes, int n_in,
                              void* d_out, int out_size, void* d_ws, size_t ws_size,
                              hipStream_t stream) {
    const float* x     = (const float*)d_in[0];
    const int*   edge  = (const int*)d_in[1];
    const int*   batch = (const int*)d_in[2];
    const float* Wrel1 = (const float*)d_in[3];
    const float* brel1 = (const float*)d_in[4];
    const float* Wroot1= (const float*)d_in[5];
    const float* Wrel2 = (const float*)d_in[6];
    const float* brel2 = (const float*)d_in[7];
    const float* Wroot2= (const float*)d_in[8];
    const float* Wrel3 = (const float*)d_in[9];
    const float* brel3 = (const float*)d_in[10];
    const float* Wroot3= (const float*)d_in[11];
    const float* Wlin  = (const float*)d_in[12];
    const float* blin  = (const float*)d_in[13];
    float* out = (float*)d_out;

    char* ws = (char*)d_ws;
    size_t p = 0;
    int* deg     = (int*)(ws + p); p += (size_t)N_NODES * 4;
    int* off     = (int*)(ws + p); p += (size_t)(N_NODES + 1) * 4;
    int* cursor  = (int*)(ws + p); p += (size_t)N_NODES * 4;
    int* partial = (int*)(ws + p); p += (size_t)(NW + 1) * 4;
    p = (p + 255) & ~(size_t)255;
    int* csr_src = (int*)(ws + p); p += (size_t)N_EDGES * 4;
    p = (p + 255) & ~(size_t)255;
    float* agg   = (float*)(ws + p); p += (size_t)N_NODES * F * 4;
    float* hA    = (float*)(ws + p); p += (size_t)N_NODES * F * 4;
    float* hB    = (float*)(ws + p); p += (size_t)N_NODES * F * 4;

    dim3 blk(256);
    const int edgeBlocks = (N_EDGES + 255) / 256;        // 3125
    const int gatherBlocks = (N_NODES * 32 + 255) / 256; // 6250 (half-wave per node)
    const int segBlocks = (NW + 3) / 4;                  // 196

    // ---- CSR build ----
    hipMemsetAsync(deg, 0, (size_t)N_NODES * 4, stream);
    hist_kernel<<<edgeBlocks, blk, 0, stream>>>(edge, deg);
    wavesum_kernel<<<segBlocks, blk, 0, stream>>>(deg, partial);
    scanp_kernel<<<1, 1024, 0, stream>>>(partial);
    offsets_kernel<<<segBlocks, blk, 0, stream>>>(deg, partial, off, cursor);
    for (int pass = 0; pass < FILL_PASSES; ++pass)
        fill_kernel<<<edgeBlocks, blk, 0, stream>>>(edge, cursor, csr_src, pass * FILL_RANGE);

    // ---- 3 GraphConv layers: gather (8-deep MLP) + GEMM (all-LDS operands) ----
    gather_kernel<<<gatherBlocks, blk, 0, stream>>>(x, off, csr_src, agg);
    gemm_kernel<<<NW, blk, 0, stream>>>(agg, x, Wrel1, brel1, Wroot1, hA, 1);

    gather_kernel<<<gatherBlocks, blk, 0, stream>>>(hA, off, csr_src, agg);
    gemm_kernel<<<NW, blk, 0, stream>>>(agg, hA, Wrel2, brel2, Wroot2, hB, 1);

    gather_kernel<<<gatherBlocks, blk, 0, stream>>>(hB, off, csr_src, agg);
    gemm_kernel<<<NW, blk, 0, stream>>>(agg, hB, Wrel3, brel3, Wroot3, hA, 0);

    // ---- fused mean-pool + head ----
    pool_head_kernel<<<N_GRAPHS, blk, 0, stream>>>(hA, batch, Wlin, blin, out);
}

// Round 12
// 360.744 us; speedup vs baseline: 1.1068x; 1.1068x over previous
//
#include <hip/hip_runtime.h>
#include <hip/hip_bf16.h>

#define N_NODES 50000
#define N_EDGES 800000
#define F 64
#define N_GRAPHS 500
#define NW ((N_NODES + 63) / 64)   // 782 node-tiles of 64
#define PADT 68                    // transposed-tile row stride (272B, 16B-aligned)
#define FILL_PASSES 4
#define FILL_RANGE ((N_NODES + FILL_PASSES - 1) / FILL_PASSES)   // 12500 dst per pass

// ---------------- CSR build step 1: deg[dst]++ ----------------
__global__ __launch_bounds__(256) void hist_kernel(
    const int* __restrict__ edge, int* __restrict__ deg)
{
    int e = blockIdx.x * 256 + threadIdx.x;
    if (e < N_EDGES) atomicAdd(&deg[edge[N_EDGES + e]], 1);
}

// ---------------- CSR build step 2a: per-64-chunk sums ----------------
__global__ __launch_bounds__(256) void wavesum_kernel(
    const int* __restrict__ deg, int* __restrict__ partial)
{
    int w = (blockIdx.x * 256 + threadIdx.x) >> 6;
    int lane = threadIdx.x & 63;
    if (w >= NW) return;
    int i = w * 64 + lane;
    int v = (i < N_NODES) ? deg[i] : 0;
#pragma unroll
    for (int d = 32; d > 0; d >>= 1) v += __shfl_xor(v, d);
    if (lane == 0) partial[w] = v;
}

// ---------------- CSR build step 2b: single-block exclusive scan of partial[NW] ----------------
__global__ __launch_bounds__(1024) void scanp_kernel(int* __restrict__ partial)
{
    __shared__ int ws[16];
    int t = threadIdx.x, lane = t & 63, wv = t >> 6;
    int v = (t < NW) ? partial[t] : 0;
    int incl = v;
#pragma unroll
    for (int d = 1; d < 64; d <<= 1) { int u = __shfl_up(incl, d); if (lane >= d) incl += u; }
    if (lane == 63) ws[wv] = incl;
    __syncthreads();
    if (wv == 0 && lane < 16) {
        int s = ws[lane];
#pragma unroll
        for (int d = 1; d < 16; d <<= 1) { int u = __shfl_up(s, d); if (lane >= d) s += u; }
        ws[lane] = s;
    }
    __syncthreads();
    int base = wv ? ws[wv - 1] : 0;
    if (t < NW) partial[t] = base + incl - v;     // exclusive scan in place
    if (t == 0) partial[NW] = ws[15];             // grand total
}

// ---------------- CSR build step 2c: per-chunk offsets ----------------
__global__ __launch_bounds__(256) void offsets_kernel(
    const int* __restrict__ deg, const int* __restrict__ partial,
    int* __restrict__ off, int* __restrict__ cursor)
{
    int w = (blockIdx.x * 256 + threadIdx.x) >> 6;
    int lane = threadIdx.x & 63;
    if (w >= NW) return;
    int i = w * 64 + lane;
    int v = (i < N_NODES) ? deg[i] : 0;
    int incl = v;
#pragma unroll
    for (int d = 1; d < 64; d <<= 1) { int u = __shfl_up(incl, d); if (lane >= d) incl += u; }
    int excl = partial[w] + incl - v;
    if (i < N_NODES) { off[i] = excl; cursor[i] = excl; }
    if (w == 0 && lane == 0) off[N_NODES] = partial[NW];
}

// ---------------- CSR build step 3: fill src lists, dst-range pass ----------------
__global__ __launch_bounds__(256) void fill_kernel(
    const int* __restrict__ edge, int* __restrict__ cursor, int* __restrict__ csr_src, int lo)
{
    int e = blockIdx.x * 256 + threadIdx.x;
    if (e < N_EDGES) {
        int dst = edge[N_EDGES + e];
        if (dst >= lo && dst < lo + FILL_RANGE) {
            int slot = atomicAdd(&cursor[dst], 1);
            csr_src[slot] = edge[e];
        }
    }
}

// ---------------- gather v3: half-wave per node, 8 row-loads in flight per lane ----------------
__global__ __launch_bounds__(256) void gather_kernel(
    const float* __restrict__ xin, const int* __restrict__ off,
    const int* __restrict__ csr_src, float* __restrict__ agg)
{
    int hw = (blockIdx.x * 256 + threadIdx.x) >> 5;   // half-wave id = node
    if (hw >= N_NODES) return;
    int hl = threadIdx.x & 31;
    int g = hl >> 4;              // slot parity 0/1
    int q = (hl & 15) << 2;       // feature quad offset

    int beg = off[hw], end = off[hw + 1];
    float4 A0 = make_float4(0.f, 0.f, 0.f, 0.f);
    float4 A1 = A0, A2 = A0, A3 = A0, A4 = A0, A5 = A0, A6 = A0, A7 = A0;

    for (int base = beg; base < end; base += 16) {
#define GSTEP(K, ACC) { int e = base + g + 2 * (K); if (e < end) { \
        const float4 v = *reinterpret_cast<const float4*>(xin + (size_t)csr_src[e] * F + q); \
        ACC.x += v.x; ACC.y += v.y; ACC.z += v.z; ACC.w += v.w; } }
        GSTEP(0, A0) GSTEP(1, A1) GSTEP(2, A2) GSTEP(3, A3)
        GSTEP(4, A4) GSTEP(5, A5) GSTEP(6, A6) GSTEP(7, A7)
#undef GSTEP
    }
    float4 s;
    s.x = ((A0.x + A1.x) + (A2.x + A3.x)) + ((A4.x + A5.x) + (A6.x + A7.x));
    s.y = ((A0.y + A1.y) + (A2.y + A3.y)) + ((A4.y + A5.y) + (A6.y + A7.y));
    s.z = ((A0.z + A1.z) + (A2.z + A3.z)) + ((A4.z + A5.z) + (A6.z + A7.z));
    s.w = ((A0.w + A1.w) + (A2.w + A3.w)) + ((A4.w + A5.w) + (A6.w + A7.w));
    s.x += __shfl_xor(s.x, 16);
    s.y += __shfl_xor(s.y, 16);
    s.z += __shfl_xor(s.z, 16);
    s.w += __shfl_xor(s.w, 16);
    if (hl < 16)
        *reinterpret_cast<float4*>(agg + (size_t)hw * F + q) = s;
}

// ---------------- gemm v3: register-tiled 4x4, transposed LDS operands, K=128 ----------------
// Block = 64-node x 64-out tile, 256 threads as 16(tm=node4) x 16(tn=out4).
// sAX[k][node]: k<64 = agg, k>=64 = x.  sW[k][out]: k<64 = Wrel, k>=64 = Wroot.
// Per k: 2 ds_read_b128 feed 16 fmacs (DS:VALU halved vs broadcast version).
__global__ __launch_bounds__(256) void gemm_kernel(
    const float* __restrict__ agg, const float* __restrict__ xin,
    const float* __restrict__ Wrel, const float* __restrict__ brel,
    const float* __restrict__ Wroot, float* __restrict__ out, int do_relu)
{
    __shared__ float sAX[128 * PADT];
    __shared__ float sW[128 * PADT];

    int tid = threadIdx.x;
    int n0 = blockIdx.x * 64;

    // ---- stage (transpose in LDS): global float4 reads coalesced; 16 b32 writes/iter ----
    for (int i = tid; i < 64 * 16; i += 256) {
        int row = i >> 4;              // node-in-tile / out index
        int c4 = (i & 15) << 2;        // k quad
        int node = n0 + row;
        float4 va = make_float4(0.f, 0.f, 0.f, 0.f), vx = va;
        if (node < N_NODES) {
            va = *reinterpret_cast<const float4*>(agg + (size_t)node * F + c4);
            vx = *reinterpret_cast<const float4*>(xin + (size_t)node * F + c4);
        }
        float4 wr = *reinterpret_cast<const float4*>(Wrel + row * F + c4);
        float4 wo = *reinterpret_cast<const float4*>(Wroot + row * F + c4);
        sAX[(c4 + 0) * PADT + row] = va.x;
        sAX[(c4 + 1) * PADT + row] = va.y;
        sAX[(c4 + 2) * PADT + row] = va.z;
        sAX[(c4 + 3) * PADT + row] = va.w;
        sAX[(64 + c4 + 0) * PADT + row] = vx.x;
        sAX[(64 + c4 + 1) * PADT + row] = vx.y;
        sAX[(64 + c4 + 2) * PADT + row] = vx.z;
        sAX[(64 + c4 + 3) * PADT + row] = vx.w;
        sW[(c4 + 0) * PADT + row] = wr.x;
        sW[(c4 + 1) * PADT + row] = wr.y;
        sW[(c4 + 2) * PADT + row] = wr.z;
        sW[(c4 + 3) * PADT + row] = wr.w;
        sW[(64 + c4 + 0) * PADT + row] = wo.x;
        sW[(64 + c4 + 1) * PADT + row] = wo.y;
        sW[(64 + c4 + 2) * PADT + row] = wo.z;
        sW[(64 + c4 + 3) * PADT + row] = wo.w;
    }
    __syncthreads();

    // ---- compute: thread (tm,tn) -> nodes tm*4..+3, outputs tn*4..+3 ----
    int tm = tid & 15, tn = tid >> 4;
    const float* pA = sAX + tm * 4;
    const float* pW = sW + tn * 4;

    float acc[4][4];
#pragma unroll
    for (int i = 0; i < 4; ++i) {
        float4 b = *reinterpret_cast<const float4*>(brel + tn * 4);
        acc[i][0] = b.x; acc[i][1] = b.y; acc[i][2] = b.z; acc[i][3] = b.w;
    }

    for (int kk = 0; kk < 128; kk += 4) {
        float4 a0 = *reinterpret_cast<const float4*>(pA + (kk + 0) * PADT);
        float4 a1 = *reinterpret_cast<const float4*>(pA + (kk + 1) * PADT);
        float4 a2 = *reinterpret_cast<const float4*>(pA + (kk + 2) * PADT);
        float4 a3 = *reinterpret_cast<const float4*>(pA + (kk + 3) * PADT);
        float4 w0 = *reinterpret_cast<const float4*>(pW + (kk + 0) * PADT);
        float4 w1 = *reinterpret_cast<const float4*>(pW + (kk + 1) * PADT);
        float4 w2 = *reinterpret_cast<const float4*>(pW + (kk + 2) * PADT);
        float4 w3 = *reinterpret_cast<const float4*>(pW + (kk + 3) * PADT);
#define FMA4(AV, WV) { \
        acc[0][0] += AV.x * WV.x; acc[0][1] += AV.x * WV.y; acc[0][2] += AV.x * WV.z; acc[0][3] += AV.x * WV.w; \
        acc[1][0] += AV.y * WV.x; acc[1][1] += AV.y * WV.y; acc[1][2] += AV.y * WV.z; acc[1][3] += AV.y * WV.w; \
        acc[2][0] += AV.z * WV.x; acc[2][1] += AV.z * WV.y; acc[2][2] += AV.z * WV.z; acc[2][3] += AV.z * WV.w; \
        acc[3][0] += AV.w * WV.x; acc[3][1] += AV.w * WV.y; acc[3][2] += AV.w * WV.z; acc[3][3] += AV.w * WV.w; }
        FMA4(a0, w0) FMA4(a1, w1) FMA4(a2, w2) FMA4(a3, w3)
#undef FMA4
    }

    if (do_relu) {
#pragma unroll
        for (int i = 0; i < 4; ++i)
#pragma unroll
            for (int j = 0; j < 4; ++j) acc[i][j] = fmaxf(acc[i][j], 0.f);
    }
#pragma unroll
    for (int i = 0; i < 4; ++i) {
        int n = n0 + tm * 4 + i;
        if (n < N_NODES)
            *reinterpret_cast<float4*>(out + (size_t)n * F + tn * 4) =
                make_float4(acc[i][0], acc[i][1], acc[i][2], acc[i][3]);
    }
}

// ---------------- fused pool (mean over contiguous node range) + head ----------------
__global__ __launch_bounds__(256) void pool_head_kernel(
    const float* __restrict__ h,
    const int* __restrict__ batch,   // sorted
    const float* __restrict__ Wlin,  // [2][64]
    const float* __restrict__ blin,  // [2]
    float* __restrict__ out)         // [N_GRAPHS][2]
{
    __shared__ float psum[4][F];
    __shared__ float pooled[F];
    int g = blockIdx.x;
    int tid = threadIdx.x, wave = tid >> 6, lane = tid & 63;

    int lo = 0, hi = N_NODES;
    while (lo < hi) { int mid = (lo + hi) >> 1; if (batch[mid] < g) lo = mid + 1; else hi = mid; }
    int s = lo;
    hi = N_NODES;
    while (lo < hi) { int mid = (lo + hi) >> 1; if (batch[mid] < g + 1) lo = mid + 1; else hi = mid; }
    int e = lo;

    float acc = 0.f;
    for (int n = s + wave; n < e; n += 4) acc += h[n * F + lane];
    psum[wave][lane] = acc;
    __syncthreads();
    if (wave == 0) {
        float p = psum[0][lane] + psum[1][lane] + psum[2][lane] + psum[3][lane];
        float c = (float)(e - s);
        pooled[lane] = p / fmaxf(c, 1.0f);
    }
    __syncthreads();
    if (tid < 2) {
        float acc2 = 0.f;
#pragma unroll
        for (int k = 0; k < F; ++k) acc2 += pooled[k] * Wlin[tid * F + k];
        out[g * 2 + tid] = acc2 + blin[tid];
    }
}

extern "C" void kernel_launch(void* const* d_in, const int* in_sizes, int n_in,
                              void* d_out, int out_size, void* d_ws, size_t ws_size,
                              hipStream_t stream) {
    const float* x     = (const float*)d_in[0];
    const int*   edge  = (const int*)d_in[1];
    const int*   batch = (const int*)d_in[2];
    const float* Wrel1 = (const float*)d_in[3];
    const float* brel1 = (const float*)d_in[4];
    const float* Wroot1= (const float*)d_in[5];
    const float* Wrel2 = (const float*)d_in[6];
    const float* brel2 = (const float*)d_in[7];
    const float* Wroot2= (const float*)d_in[8];
    const float* Wrel3 = (const float*)d_in[9];
    const float* brel3 = (const float*)d_in[10];
    const float* Wroot3= (const float*)d_in[11];
    const float* Wlin  = (const float*)d_in[12];
    const float* blin  = (const float*)d_in[13];
    float* out = (float*)d_out;

    char* ws = (char*)d_ws;
    size_t p = 0;
    int* deg     = (int*)(ws + p); p += (size_t)N_NODES * 4;
    int* off     = (int*)(ws + p); p += (size_t)(N_NODES + 1) * 4;
    int* cursor  = (int*)(ws + p); p += (size_t)N_NODES * 4;
    int* partial = (int*)(ws + p); p += (size_t)(NW + 1) * 4;
    p = (p + 255) & ~(size_t)255;
    int* csr_src = (int*)(ws + p); p += (size_t)N_EDGES * 4;
    p = (p + 255) & ~(size_t)255;
    float* agg   = (float*)(ws + p); p += (size_t)N_NODES * F * 4;
    float* hA    = (float*)(ws + p); p += (size_t)N_NODES * F * 4;
    float* hB    = (float*)(ws + p); p += (size_t)N_NODES * F * 4;

    dim3 blk(256);
    const int edgeBlocks = (N_EDGES + 255) / 256;        // 3125
    const int gatherBlocks = (N_NODES * 32 + 255) / 256; // 6250 (half-wave per node)
    const int segBlocks = (NW + 3) / 4;                  // 196

    // ---- CSR build ----
    hipMemsetAsync(deg, 0, (size_t)N_NODES * 4, stream);
    hist_kernel<<<edgeBlocks, blk, 0, stream>>>(edge, deg);
    wavesum_kernel<<<segBlocks, blk, 0, stream>>>(deg, partial);
    scanp_kernel<<<1, 1024, 0, stream>>>(partial);
    offsets_kernel<<<segBlocks, blk, 0, stream>>>(deg, partial, off, cursor);
    for (int pass = 0; pass < FILL_PASSES; ++pass)
        fill_kernel<<<edgeBlocks, blk, 0, stream>>>(edge, cursor, csr_src, pass * FILL_RANGE);

    // ---- 3 GraphConv layers: gather (8-deep MLP) + register-tiled GEMM ----
    gather_kernel<<<gatherBlocks, blk, 0, stream>>>(x, off, csr_src, agg);
    gemm_kernel<<<NW, blk, 0, stream>>>(agg, x, Wrel1, brel1, Wroot1, hA, 1);

    gather_kernel<<<gatherBlocks, blk, 0, stream>>>(hA, off, csr_src, agg);
    gemm_kernel<<<NW, blk, 0, stream>>>(agg, hA, Wrel2, brel2, Wroot2, hB, 1);

    gather_kernel<<<gatherBlocks, blk, 0, stream>>>(hB, off, csr_src, agg);
    gemm_kernel<<<NW, blk, 0, stream>>>(agg, hB, Wrel3, brel3, Wroot3, hA, 0);

    // ---- fused mean-pool + head ----
    pool_head_kernel<<<N_GRAPHS, blk, 0, stream>>>(hA, batch, Wlin, blin, out);
}

// Round 13
// 350.865 us; speedup vs baseline: 1.1379x; 1.0282x over previous
//
#include <hip/hip_runtime.h>
#include <hip/hip_bf16.h>

#define N_NODES 50000
#define N_EDGES 800000
#define F 64
#define N_GRAPHS 500
#define NW ((N_NODES + 63) / 64)   // 782 node-tiles of 64
#define PADT 68                    // k-major row stride (floats), 16B-aligned
#define FILL_PASSES 4
#define FILL_RANGE ((N_NODES + FILL_PASSES - 1) / FILL_PASSES)   // 12500 dst per pass

// ---------------- CSR build step 1: deg[dst]++ ----------------
__global__ __launch_bounds__(256) void hist_kernel(
    const int* __restrict__ edge, int* __restrict__ deg)
{
    int e = blockIdx.x * 256 + threadIdx.x;
    if (e < N_EDGES) atomicAdd(&deg[edge[N_EDGES + e]], 1);
}

// ---------------- CSR build step 2a: per-64-chunk sums ----------------
__global__ __launch_bounds__(256) void wavesum_kernel(
    const int* __restrict__ deg, int* __restrict__ partial)
{
    int w = (blockIdx.x * 256 + threadIdx.x) >> 6;
    int lane = threadIdx.x & 63;
    if (w >= NW) return;
    int i = w * 64 + lane;
    int v = (i < N_NODES) ? deg[i] : 0;
#pragma unroll
    for (int d = 32; d > 0; d >>= 1) v += __shfl_xor(v, d);
    if (lane == 0) partial[w] = v;
}

// ---------------- CSR build step 2b: single-block exclusive scan of partial[NW] ----------------
__global__ __launch_bounds__(1024) void scanp_kernel(int* __restrict__ partial)
{
    __shared__ int ws[16];
    int t = threadIdx.x, lane = t & 63, wv = t >> 6;
    int v = (t < NW) ? partial[t] : 0;
    int incl = v;
#pragma unroll
    for (int d = 1; d < 64; d <<= 1) { int u = __shfl_up(incl, d); if (lane >= d) incl += u; }
    if (lane == 63) ws[wv] = incl;
    __syncthreads();
    if (wv == 0 && lane < 16) {
        int s = ws[lane];
#pragma unroll
        for (int d = 1; d < 16; d <<= 1) { int u = __shfl_up(s, d); if (lane >= d) s += u; }
        ws[lane] = s;
    }
    __syncthreads();
    int base = wv ? ws[wv - 1] : 0;
    if (t < NW) partial[t] = base + incl - v;     // exclusive scan in place
    if (t == 0) partial[NW] = ws[15];             // grand total
}

// ---------------- CSR build step 2c: per-chunk offsets ----------------
__global__ __launch_bounds__(256) void offsets_kernel(
    const int* __restrict__ deg, const int* __restrict__ partial,
    int* __restrict__ off, int* __restrict__ cursor)
{
    int w = (blockIdx.x * 256 + threadIdx.x) >> 6;
    int lane = threadIdx.x & 63;
    if (w >= NW) return;
    int i = w * 64 + lane;
    int v = (i < N_NODES) ? deg[i] : 0;
    int incl = v;
#pragma unroll
    for (int d = 1; d < 64; d <<= 1) { int u = __shfl_up(incl, d); if (lane >= d) incl += u; }
    int excl = partial[w] + incl - v;
    if (i < N_NODES) { off[i] = excl; cursor[i] = excl; }
    if (w == 0 && lane == 0) off[N_NODES] = partial[NW];
}

// ---------------- CSR build step 3: fill src lists, dst-range pass ----------------
__global__ __launch_bounds__(256) void fill_kernel(
    const int* __restrict__ edge, int* __restrict__ cursor, int* __restrict__ csr_src, int lo)
{
    int e = blockIdx.x * 256 + threadIdx.x;
    if (e < N_EDGES) {
        int dst = edge[N_EDGES + e];
        if (dst >= lo && dst < lo + FILL_RANGE) {
            int slot = atomicAdd(&cursor[dst], 1);
            csr_src[slot] = edge[e];
        }
    }
}

// ---------------- gather v3: half-wave per node, 8 row-loads in flight per lane ----------------
__global__ __launch_bounds__(256) void gather_kernel(
    const float* __restrict__ xin, const int* __restrict__ off,
    const int* __restrict__ csr_src, float* __restrict__ agg)
{
    int hw = (blockIdx.x * 256 + threadIdx.x) >> 5;   // half-wave id = node
    if (hw >= N_NODES) return;
    int hl = threadIdx.x & 31;
    int g = hl >> 4;              // slot parity 0/1
    int q = (hl & 15) << 2;       // feature quad offset

    int beg = off[hw], end = off[hw + 1];
    float4 A0 = make_float4(0.f, 0.f, 0.f, 0.f);
    float4 A1 = A0, A2 = A0, A3 = A0, A4 = A0, A5 = A0, A6 = A0, A7 = A0;

    for (int base = beg; base < end; base += 16) {
#define GSTEP(K, ACC) { int e = base + g + 2 * (K); if (e < end) { \
        const float4 v = *reinterpret_cast<const float4*>(xin + (size_t)csr_src[e] * F + q); \
        ACC.x += v.x; ACC.y += v.y; ACC.z += v.z; ACC.w += v.w; } }
        GSTEP(0, A0) GSTEP(1, A1) GSTEP(2, A2) GSTEP(3, A3)
        GSTEP(4, A4) GSTEP(5, A5) GSTEP(6, A6) GSTEP(7, A7)
#undef GSTEP
    }
    float4 s;
    s.x = ((A0.x + A1.x) + (A2.x + A3.x)) + ((A4.x + A5.x) + (A6.x + A7.x));
    s.y = ((A0.y + A1.y) + (A2.y + A3.y)) + ((A4.y + A5.y) + (A6.y + A7.y));
    s.z = ((A0.z + A1.z) + (A2.z + A3.z)) + ((A4.z + A5.z) + (A6.z + A7.z));
    s.w = ((A0.w + A1.w) + (A2.w + A3.w)) + ((A4.w + A5.w) + (A6.w + A7.w));
    s.x += __shfl_xor(s.x, 16);
    s.y += __shfl_xor(s.y, 16);
    s.z += __shfl_xor(s.z, 16);
    s.w += __shfl_xor(s.w, 16);
    if (hl < 16)
        *reinterpret_cast<float4*>(agg + (size_t)hw * F + q) = s;
}

// ---------------- gemm v4: register-tiled 4x4, split-K chunks, swizzled transpose ----------------
// Block = 64-node x 64-out tile, 256 threads as 16(tm=node4) x 16(tn=out4).
// Chunk 0: A=agg, W=Wrel (k 0..63); chunk 1: A=x, W=Wroot. One 2x17.4KB LDS footprint,
// reused across chunks -> 34.8KB -> 4 blocks/CU (2x the occupancy of v3).
// Swizzle: element (k,row) stored at row' = (row + 4*(k>>2)) & 63. Staging writes spread
// across 8 banks (2-way, free); compute reads stay 4-contiguous 16B-aligned b128.
__global__ __launch_bounds__(256) void gemm_kernel(
    const float* __restrict__ agg, const float* __restrict__ xin,
    const float* __restrict__ Wrel, const float* __restrict__ brel,
    const float* __restrict__ Wroot, float* __restrict__ out, int do_relu)
{
    __shared__ float sA[64 * PADT];
    __shared__ float sW[64 * PADT];

    int tid = threadIdx.x;
    int n0 = blockIdx.x * 64;
    int tm = tid & 15, tn = tid >> 4;

    float acc[4][4];
    {
        float4 b = *reinterpret_cast<const float4*>(brel + tn * 4);
#pragma unroll
        for (int i = 0; i < 4; ++i) {
            acc[i][0] = b.x; acc[i][1] = b.y; acc[i][2] = b.z; acc[i][3] = b.w;
        }
    }

#pragma unroll
    for (int half = 0; half < 2; ++half) {
        const float* __restrict__ Asrc = half ? xin : agg;
        const float* __restrict__ Wsrc = half ? Wroot : Wrel;
        if (half) __syncthreads();   // previous compute must finish before overwrite

        // ---- stage chunk (swizzled transpose; writes 2-way conflicted = free) ----
        for (int i = tid; i < 64 * 16; i += 256) {
            int row = i >> 4;              // node-in-tile / out index
            int c4 = (i & 15) << 2;        // k quad base; rot = 4*(k>>2) = c4 for all j
            int node = n0 + row;
            float4 va = make_float4(0.f, 0.f, 0.f, 0.f);
            if (node < N_NODES)
                va = *reinterpret_cast<const float4*>(Asrc + (size_t)node * F + c4);
            float4 wv = *reinterpret_cast<const float4*>(Wsrc + row * F + c4);
            int r2 = (row + c4) & 63;      // rotated row
            sA[(c4 + 0) * PADT + r2] = va.x;
            sA[(c4 + 1) * PADT + r2] = va.y;
            sA[(c4 + 2) * PADT + r2] = va.z;
            sA[(c4 + 3) * PADT + r2] = va.w;
            sW[(c4 + 0) * PADT + r2] = wv.x;
            sW[(c4 + 1) * PADT + r2] = wv.y;
            sW[(c4 + 2) * PADT + r2] = wv.z;
            sW[(c4 + 3) * PADT + r2] = wv.w;
        }
        __syncthreads();

        // ---- compute 64 k of this chunk ----
        for (int kk = 0; kk < 64; kk += 4) {
            int rm = (tm * 4 + kk) & 63;   // rotated read row for A (rot = kk within quad)
            int rn = (tn * 4 + kk) & 63;   // rotated read row for W
            float4 a0 = *reinterpret_cast<const float4*>(sA + (kk + 0) * PADT + rm);
            float4 a1 = *reinterpret_cast<const float4*>(sA + (kk + 1) * PADT + rm);
            float4 a2 = *reinterpret_cast<const float4*>(sA + (kk + 2) * PADT + rm);
            float4 a3 = *reinterpret_cast<const float4*>(sA + (kk + 3) * PADT + rm);
            float4 w0 = *reinterpret_cast<const float4*>(sW + (kk + 0) * PADT + rn);
            float4 w1 = *reinterpret_cast<const float4*>(sW + (kk + 1) * PADT + rn);
            float4 w2 = *reinterpret_cast<const float4*>(sW + (kk + 2) * PADT + rn);
            float4 w3 = *reinterpret_cast<const float4*>(sW + (kk + 3) * PADT + rn);
#define FMA4(AV, WV) { \
            acc[0][0] += AV.x * WV.x; acc[0][1] += AV.x * WV.y; acc[0][2] += AV.x * WV.z; acc[0][3] += AV.x * WV.w; \
            acc[1][0] += AV.y * WV.x; acc[1][1] += AV.y * WV.y; acc[1][2] += AV.y * WV.z; acc[1][3] += AV.y * WV.w; \
            acc[2][0] += AV.z * WV.x; acc[2][1] += AV.z * WV.y; acc[2][2] += AV.z * WV.z; acc[2][3] += AV.z * WV.w; \
            acc[3][0] += AV.w * WV.x; acc[3][1] += AV.w * WV.y; acc[3][2] += AV.w * WV.z; acc[3][3] += AV.w * WV.w; }
            FMA4(a0, w0) FMA4(a1, w1) FMA4(a2, w2) FMA4(a3, w3)
#undef FMA4
        }
    }

    if (do_relu) {
#pragma unroll
        for (int i = 0; i < 4; ++i)
#pragma unroll
            for (int j = 0; j < 4; ++j) acc[i][j] = fmaxf(acc[i][j], 0.f);
    }
#pragma unroll
    for (int i = 0; i < 4; ++i) {
        int n = n0 + tm * 4 + i;
        if (n < N_NODES)
            *reinterpret_cast<float4*>(out + (size_t)n * F + tn * 4) =
                make_float4(acc[i][0], acc[i][1], acc[i][2], acc[i][3]);
    }
}

// ---------------- fused pool (mean over contiguous node range) + head ----------------
__global__ __launch_bounds__(256) void pool_head_kernel(
    const float* __restrict__ h,
    const int* __restrict__ batch,   // sorted
    const float* __restrict__ Wlin,  // [2][64]
    const float* __restrict__ blin,  // [2]
    float* __restrict__ out)         // [N_GRAPHS][2]
{
    __shared__ float psum[4][F];
    __shared__ float pooled[F];
    int g = blockIdx.x;
    int tid = threadIdx.x, wave = tid >> 6, lane = tid & 63;

    int lo = 0, hi = N_NODES;
    while (lo < hi) { int mid = (lo + hi) >> 1; if (batch[mid] < g) lo = mid + 1; else hi = mid; }
    int s = lo;
    hi = N_NODES;
    while (lo < hi) { int mid = (lo + hi) >> 1; if (batch[mid] < g + 1) lo = mid + 1; else hi = mid; }
    int e = lo;

    float acc = 0.f;
    for (int n = s + wave; n < e; n += 4) acc += h[n * F + lane];
    psum[wave][lane] = acc;
    __syncthreads();
    if (wave == 0) {
        float p = psum[0][lane] + psum[1][lane] + psum[2][lane] + psum[3][lane];
        float c = (float)(e - s);
        pooled[lane] = p / fmaxf(c, 1.0f);
    }
    __syncthreads();
    if (tid < 2) {
        float acc2 = 0.f;
#pragma unroll
        for (int k = 0; k < F; ++k) acc2 += pooled[k] * Wlin[tid * F + k];
        out[g * 2 + tid] = acc2 + blin[tid];
    }
}

extern "C" void kernel_launch(void* const* d_in, const int* in_sizes, int n_in,
                              void* d_out, int out_size, void* d_ws, size_t ws_size,
                              hipStream_t stream) {
    const float* x     = (const float*)d_in[0];
    const int*   edge  = (const int*)d_in[1];
    const int*   batch = (const int*)d_in[2];
    const float* Wrel1 = (const float*)d_in[3];
    const float* brel1 = (const float*)d_in[4];
    const float* Wroot1= (const float*)d_in[5];
    const float* Wrel2 = (const float*)d_in[6];
    const float* brel2 = (const float*)d_in[7];
    const float* Wroot2= (const float*)d_in[8];
    const float* Wrel3 = (const float*)d_in[9];
    const float* brel3 = (const float*)d_in[10];
    const float* Wroot3= (const float*)d_in[11];
    const float* Wlin  = (const float*)d_in[12];
    const float* blin  = (const float*)d_in[13];
    float* out = (float*)d_out;

    char* ws = (char*)d_ws;
    size_t p = 0;
    int* deg     = (int*)(ws + p); p += (size_t)N_NODES * 4;
    int* off     = (int*)(ws + p); p += (size_t)(N_NODES + 1) * 4;
    int* cursor  = (int*)(ws + p); p += (size_t)N_NODES * 4;
    int* partial = (int*)(ws + p); p += (size_t)(NW + 1) * 4;
    p = (p + 255) & ~(size_t)255;
    int* csr_src = (int*)(ws + p); p += (size_t)N_EDGES * 4;
    p = (p + 255) & ~(size_t)255;
    float* agg   = (float*)(ws + p); p += (size_t)N_NODES * F * 4;
    float* hA    = (float*)(ws + p); p += (size_t)N_NODES * F * 4;
    float* hB    = (float*)(ws + p); p += (size_t)N_NODES * F * 4;

    dim3 blk(256);
    const int edgeBlocks = (N_EDGES + 255) / 256;        // 3125
    const int gatherBlocks = (N_NODES * 32 + 255) / 256; // 6250 (half-wave per node)
    const int segBlocks = (NW + 3) / 4;                  // 196

    // ---- CSR build ----
    hipMemsetAsync(deg, 0, (size_t)N_NODES * 4, stream);
    hist_kernel<<<edgeBlocks, blk, 0, stream>>>(edge, deg);
    wavesum_kernel<<<segBlocks, blk, 0, stream>>>(deg, partial);
    scanp_kernel<<<1, 1024, 0, stream>>>(partial);
    offsets_kernel<<<segBlocks, blk, 0, stream>>>(deg, partial, off, cursor);
    for (int pass = 0; pass < FILL_PASSES; ++pass)
        fill_kernel<<<edgeBlocks, blk, 0, stream>>>(edge, cursor, csr_src, pass * FILL_RANGE);

    // ---- 3 GraphConv layers: gather (8-deep MLP) + register-tiled swizzled GEMM ----
    gather_kernel<<<gatherBlocks, blk, 0, stream>>>(x, off, csr_src, agg);
    gemm_kernel<<<NW, blk, 0, stream>>>(agg, x, Wrel1, brel1, Wroot1, hA, 1);

    gather_kernel<<<gatherBlocks, blk, 0, stream>>>(hA, off, csr_src, agg);
    gemm_kernel<<<NW, blk, 0, stream>>>(agg, hA, Wrel2, brel2, Wroot2, hB, 1);

    gather_kernel<<<gatherBlocks, blk, 0, stream>>>(hB, off, csr_src, agg);
    gemm_kernel<<<NW, blk, 0, stream>>>(agg, hB, Wrel3, brel3, Wroot3, hA, 0);

    // ---- fused mean-pool + head ----
    pool_head_kernel<<<N_GRAPHS, blk, 0, stream>>>(hA, batch, Wlin, blin, out);
}